// Round 7
// baseline (358.720 us; speedup 1.0000x reference)
//
#include <hip/hip_runtime.h>
#include <hip/hip_bf16.h>
#include <stdint.h>

#define BATCH   16384
#define EXPERTS 8
#define IN_DIM  1024
#define OUT_DIM 1024
#define NT      128            // K-tiles of 64 over K = 8*1024

typedef unsigned short u16;
typedef short  bf16x8 __attribute__((ext_vector_type(8)));
typedef float  f32x4  __attribute__((ext_vector_type(4)));

__device__ __forceinline__ u16 f2bf(float f) {
  uint32_t u = __float_as_uint(f);
  u += 0x7fffu + ((u >> 16) & 1u);   // RNE
  return (u16)(u >> 16);
}

// scale 8 packed bf16 by s (f32 math, RNE repack)
__device__ __forceinline__ bf16x8 scale8(bf16x8 xv, float s) {
  union { bf16x8 v; uint32_t u[4]; } in, out;
  in.v = xv;
#pragma unroll
  for (int i = 0; i < 4; ++i) {
    float lo = __uint_as_float(in.u[i] << 16);
    float hi = __uint_as_float(in.u[i] & 0xffff0000u);
    uint32_t a = f2bf(lo * s), b = f2bf(hi * s);
    out.u[i] = a | (b << 16);
  }
  return out.v;
}

#define GLDS16(g, l)                                                      \
  __builtin_amdgcn_global_load_lds(                                       \
      (const __attribute__((address_space(1))) void*)(g),                 \
      (__attribute__((address_space(3))) void*)(l), 16, 0, 0)

#define MFMA_BF16 __builtin_amdgcn_mfma_f32_16x16x32_bf16

// ---------------- kernel 1: x fp32 -> bf16 ----------------
__global__ void cvt_x(const float* __restrict__ x, u16* __restrict__ xb) {
  size_t i = ((size_t)blockIdx.x * 256 + threadIdx.x) * 4;
  float4 v = *reinterpret_cast<const float4*>(x + i);
  ushort4 o;
  o.x = f2bf(v.x); o.y = f2bf(v.y); o.z = f2bf(v.z); o.w = f2bf(v.w);
  *reinterpret_cast<ushort4*>(xb + i) = o;
}

// ------- kernel 2: W[e][i][o] fp32 -> Wbt[e][o][i] bf16 (transpose) -------
__global__ void cvt_w(const float* __restrict__ W, u16* __restrict__ wbt) {
  __shared__ u16 t[64][72];
  const int e  = blockIdx.z;
  const int i0 = blockIdx.x * 64;
  const int o0 = blockIdx.y * 64;
  const int tid = threadIdx.x;
  const int c  = (tid & 15) * 4;
  const int r_ = tid >> 4;
  const float* src = W + ((size_t)e << 20);
#pragma unroll
  for (int p = 0; p < 4; ++p) {
    int r = r_ + p * 16;
    float4 v = *reinterpret_cast<const float4*>(src + (size_t)(i0 + r) * 1024 + o0 + c);
    t[r][c + 0] = f2bf(v.x); t[r][c + 1] = f2bf(v.y);
    t[r][c + 2] = f2bf(v.z); t[r][c + 3] = f2bf(v.w);
  }
  __syncthreads();
  u16* dst = wbt + ((size_t)e << 20);
#pragma unroll
  for (int p = 0; p < 4; ++p) {
    int orow = r_ + p * 16;
    ushort4 u;
    u.x = t[c + 0][orow]; u.y = t[c + 1][orow];
    u.z = t[c + 2][orow]; u.w = t[c + 3][orow];
    *reinterpret_cast<ushort4*>(dst + (size_t)(o0 + orow) * 1024 + i0 + c) = u;
  }
}

// ---------------- kernel 3: fused Z-GEMM, BM=BN=256, 4-phase/K-tile -------
// y = Z @ Wflat^T, Z[b, e*1024+i] = w[b,e]*x[b,i] built on the fly:
// A staged reg-path (load xb, scale by wl, swizzled ds_write); B via
// global_load_lds (pre-swizzled source). 8 waves 2Mx4N, per-wave 128x64,
// acc[8][4] f32x4 = 128 VGPR, single accumulator (no fold).
// Phases P0..P3 per K-tile t (16 MFMA each):
//  P0: reads a(kf0,m0-3)+b(kf0,n0-3)+wl | GLDS B(t+1)Q0,Q1 | x-loads(t+1)x4
//  P1: reads a(kf0,m4-7)                | GLDS B(t+1)Q2,Q3
//  P2: reads a(kf1,m0-3)+b(kf1)        | vmcnt(2) | dsw A(t+1)H0
//  P3: reads a(kf1,m4-7)               | vmcnt(0) | dsw A(t+1)H1
// Each phase: ... barrier; lgkmcnt(0); sched_barrier; setprio(1); MFMA;
// setprio(0); barrier.  P3's vmcnt(0) drains ALL tile-t+1 staging >=2
// barriers before its first read -> race-free under any reorder.
// LDS (u16 elems): A slots @0,@16384 (32KB ea); B slots @32768,@49152
// (32KB ea); wl f32[8][256] @65536 (8KB). Total 69632 elems = 136KB.
__global__ __launch_bounds__(512, 2)
void zgemm(const u16* __restrict__ xb, const u16* __restrict__ wbt,
           const float* __restrict__ wts, const float* __restrict__ bias,
           float* __restrict__ y) {
  __shared__ u16 sm[69632];
  char* smb = (char*)sm;
  float* wl = (float*)(sm + 65536);

  const int tid = threadIdx.x;
  const int l   = tid & 63;
  const int w   = tid >> 6;
  const int wm  = w >> 2;                 // 0..1
  const int wn  = w & 3;                  // 0..3
  const int n0  = (blockIdx.x & 3) * 256; // XCD (bid&7) hosts one N-panel
  const int b0  = (blockIdx.x >> 2) * 256;

  // ---- stage expert weights wl[e][256]
#pragma unroll
  for (int i = 0; i < 4; ++i) {
    const int flat = tid + i * 512;
    const int ee = flat & 7, r = flat >> 3;
    wl[ee * 256 + r] = wts[(size_t)(b0 + r) * EXPERTS + ee];
  }
  asm volatile("s_waitcnt lgkmcnt(0)" ::: "memory");
  __builtin_amdgcn_s_barrier();

  // ---- staging geometry
  const int r0 = tid >> 3;                       // A row base (0..63)
  const int cA = tid & 7;                        // A k-chunk
  const u16* xA = xb + (size_t)(b0 + r0) * IN_DIM + cA * 8;
  const int awz = (cA * 16) ^ ((r0 & 7) << 4);   // dsw swizzled byte off
  const int chunkB = ((l & 7) ^ (l >> 3)) << 3;  // pre-swizzled B src chunk
  const u16* pBq = wbt + (size_t)(n0 + (tid >> 3)) * 1024 + chunkB;

  // ---- fragment read keys
  const int l15  = l & 15;
  const int kbase = (((l >> 4) << 4)) ^ ((l & 7) << 4);  // kf0; kf1 = ^64
  const int arow = (wm * 128 + l15) * 128;               // + m*2048
  const int brow = (wn * 64 + l15) * 128;                // + nf*2048

  f32x4 acc[8][4];
#pragma unroll
  for (int m = 0; m < 8; ++m)
#pragma unroll
    for (int n = 0; n < 4; ++n) acc[m][n] = (f32x4){0.f, 0.f, 0.f, 0.f};

#define STGB(q, baseE, ev, kv)                                             \
  GLDS16(pBq + (size_t)(ev) * 1048576 + (size_t)(q) * 65536 + (kv) * 64,   \
         sm + (baseE) + (q) * 4096 + (w << 9))

  // ---- prologue: A(0) reg-staged, B(0) GLDS; drain fully; barrier
  {
    bf16x8 xq[4]; float wv[4];
#pragma unroll
    for (int j = 0; j < 4; ++j) {
      xq[j] = *(const bf16x8*)(xA + j * 65536);
      wv[j] = wl[r0 + (j << 6)];                 // e=0
    }
#pragma unroll
    for (int j = 0; j < 4; ++j)
      *(bf16x8*)(smb + (r0 + (j << 6)) * 128 + awz) = scale8(xq[j], wv[j]);
    STGB(0, 32768, 0, 0); STGB(1, 32768, 0, 0);
    STGB(2, 32768, 0, 0); STGB(3, 32768, 0, 0);
    asm volatile("s_waitcnt vmcnt(0)" ::: "memory");
    asm volatile("s_waitcnt lgkmcnt(0)" ::: "memory");
    __builtin_amdgcn_s_barrier();
  }

#define CLUSTER(AV, MBASE, KOFF)                                           \
  __builtin_amdgcn_s_barrier();                                            \
  asm volatile("s_waitcnt lgkmcnt(0)" ::: "memory");                       \
  __builtin_amdgcn_sched_barrier(0);                                       \
  __builtin_amdgcn_s_setprio(1);                                           \
  _Pragma("unroll")                                                        \
  for (int m = 0; m < 4; ++m)                                              \
    _Pragma("unroll")                                                      \
    for (int n = 0; n < 4; ++n)                                            \
      acc[(MBASE) + m][n] = MFMA_BF16(AV[m], b[n], acc[(MBASE) + m][n], 0, 0, 0); \
  __builtin_amdgcn_s_setprio(0);                                           \
  __builtin_amdgcn_s_barrier();

#pragma unroll 1
  for (int t = 0; t < NT; ++t) {
    const int kt1 = (t + 1) & 15;
    const int e1  = ((t + 1) >> 4) & 7;          // wraps at t=127 (harmless)
    const int ArB = (t & 1) << 15;               // A read base (bytes)
    const int AwB = ((t + 1) & 1) << 15;         // A write base (bytes)
    const int BrB = 65536 + ((t & 1) << 15);     // B read base (bytes)
    const int BwE = 32768 + (((t + 1) & 1) << 14); // B write base (elems)

    bf16x8 a[4], b[4], xq[4];
    float wv[4];

    // ================= P0 : kf0, m0-3 =================
#pragma unroll
    for (int m = 0; m < 4; ++m)
      a[m] = *(const bf16x8*)(smb + ArB + arow + m * 2048 + kbase);
#pragma unroll
    for (int n = 0; n < 4; ++n)
      b[n] = *(const bf16x8*)(smb + BrB + brow + n * 2048 + kbase);
#pragma unroll
    for (int j = 0; j < 4; ++j) wv[j] = wl[e1 * 256 + r0 + (j << 6)];
    STGB(0, BwE, e1, kt1); STGB(1, BwE, e1, kt1);
#pragma unroll
    for (int j = 0; j < 4; ++j)
      xq[j] = *(const bf16x8*)(xA + j * 65536 + kt1 * 64);
    CLUSTER(a, 0, 0)

    // ================= P1 : kf0, m4-7 =================
    bf16x8 a2[4];
#pragma unroll
    for (int m = 0; m < 4; ++m)
      a2[m] = *(const bf16x8*)(smb + ArB + arow + (m + 4) * 2048 + kbase);
    STGB(2, BwE, e1, kt1); STGB(3, BwE, e1, kt1);
    CLUSTER(a2, 4, 0)

    // ================= P2 : kf1, m0-3 =================
#pragma unroll
    for (int m = 0; m < 4; ++m)
      a[m] = *(const bf16x8*)(smb + ArB + arow + m * 2048 + (kbase ^ 64));
#pragma unroll
    for (int n = 0; n < 4; ++n)
      b[n] = *(const bf16x8*)(smb + BrB + brow + n * 2048 + (kbase ^ 64));
    asm volatile("s_waitcnt vmcnt(2)" ::: "memory");   // x drained (Q2,Q3 fly)
    *(bf16x8*)(smb + AwB + (r0      ) * 128 + awz) = scale8(xq[0], wv[0]);
    *(bf16x8*)(smb + AwB + (r0 +  64) * 128 + awz) = scale8(xq[1], wv[1]);
    CLUSTER(a, 0, 64)

    // ================= P3 : kf1, m4-7 =================
#pragma unroll
    for (int m = 0; m < 4; ++m)
      a2[m] = *(const bf16x8*)(smb + ArB + arow + (m + 4) * 2048 + (kbase ^ 64));
    asm volatile("s_waitcnt vmcnt(0)" ::: "memory");   // all t+1 staging done
    *(bf16x8*)(smb + AwB + (r0 + 128) * 128 + awz) = scale8(xq[2], wv[2]);
    *(bf16x8*)(smb + AwB + (r0 + 192) * 128 + awz) = scale8(xq[3], wv[3]);
    CLUSTER(a2, 4, 64)
  }
  asm volatile("s_waitcnt vmcnt(0)" ::: "memory");

  // ---- epilogue: bias term + store fp32
  float bv[4][8];
#pragma unroll
  for (int n = 0; n < 4; ++n) {
    const int c = n0 + wn * 64 + n * 16 + l15;
#pragma unroll
    for (int ee = 0; ee < 8; ++ee) bv[n][ee] = bias[ee * OUT_DIM + c];
  }
#pragma unroll
  for (int m = 0; m < 8; ++m) {
    const int wrow = wm * 128 + m * 16 + ((l >> 4) << 2);
    f32x4 wv8[8];
#pragma unroll
    for (int ee = 0; ee < 8; ++ee) wv8[ee] = *(const f32x4*)(wl + ee * 256 + wrow);
#pragma unroll
    for (int n = 0; n < 4; ++n) {
      const int c = n0 + wn * 64 + n * 16 + l15;
#pragma unroll
      for (int j = 0; j < 4; ++j) {
        float v = acc[m][n][j];
#pragma unroll
        for (int ee = 0; ee < 8; ++ee) v += wv8[ee][j] * bv[n][ee];
        y[(size_t)(b0 + wrow + j) * OUT_DIM + c] = v;
      }
    }
  }
}

extern "C" void kernel_launch(void* const* d_in, const int* in_sizes, int n_in,
                              void* d_out, int out_size, void* d_ws, size_t ws_size,
                              hipStream_t stream) {
  const float* x    = (const float*)d_in[0];
  const float* wts  = (const float*)d_in[1];
  const float* W    = (const float*)d_in[2];
  const float* bias = (const float*)d_in[3];
  float* y = (float*)d_out;

  const size_t xb_elems = (size_t)BATCH * IN_DIM;                 // 32 MB bf16
  const size_t wb_elems = (size_t)EXPERTS * IN_DIM * OUT_DIM;     // 16 MB bf16
  if (ws_size < (xb_elems + wb_elems) * sizeof(u16)) return;      // loud failure
  u16* xb  = (u16*)d_ws;
  u16* wbt = xb + xb_elems;

  cvt_x<<<(BATCH * IN_DIM) / (4 * 256), 256, 0, stream>>>(x, xb);
  cvt_w<<<dim3(IN_DIM / 64, OUT_DIM / 64, EXPERTS), 256, 0, stream>>>(W, wbt);
  zgemm<<<dim3((BATCH / 256) * (OUT_DIM / 256)), 512, 0, stream>>>(xb, wbt, wts, bias, y);
}

// Round 9
// 287.864 us; speedup vs baseline: 1.2461x; 1.2461x over previous
//
#include <hip/hip_runtime.h>
#include <hip/hip_bf16.h>
#include <stdint.h>

#define BATCH   16384
#define EXPERTS 8
#define IN_DIM  1024
#define OUT_DIM 1024

typedef unsigned short u16;
typedef short  bf16x8 __attribute__((ext_vector_type(8)));
typedef float  f32x4  __attribute__((ext_vector_type(4)));

__device__ __forceinline__ u16 f2bf(float f) {
  uint32_t u = __float_as_uint(f);
  u += 0x7fffu + ((u >> 16) & 1u);   // RNE
  return (u16)(u >> 16);
}

#define GLDS16(g, l)                                                      \
  __builtin_amdgcn_global_load_lds(                                       \
      (const __attribute__((address_space(1))) void*)(g),                 \
      (__attribute__((address_space(3))) void*)(l), 16, 0, 0)

#define MFMA_BF16 __builtin_amdgcn_mfma_f32_16x16x32_bf16

// ---------------- kernel 1: x fp32 -> bf16 ----------------
__global__ void cvt_x(const float* __restrict__ x, u16* __restrict__ xb) {
  size_t i = ((size_t)blockIdx.x * 256 + threadIdx.x) * 4;
  float4 v = *reinterpret_cast<const float4*>(x + i);
  ushort4 o;
  o.x = f2bf(v.x); o.y = f2bf(v.y); o.z = f2bf(v.z); o.w = f2bf(v.w);
  *reinterpret_cast<ushort4*>(xb + i) = o;
}

// ------- kernel 2: W[e][i][o] fp32 -> Wbt[e][o][i] bf16 (transpose) -------
__global__ void cvt_w(const float* __restrict__ W, u16* __restrict__ wbt) {
  __shared__ u16 t[64][72];
  const int e  = blockIdx.z;
  const int i0 = blockIdx.x * 64;
  const int o0 = blockIdx.y * 64;
  const int tid = threadIdx.x;
  const int c  = (tid & 15) * 4;
  const int r_ = tid >> 4;
  const float* src = W + ((size_t)e << 20);
#pragma unroll
  for (int p = 0; p < 4; ++p) {
    int r = r_ + p * 16;
    float4 v = *reinterpret_cast<const float4*>(src + (size_t)(i0 + r) * 1024 + o0 + c);
    t[r][c + 0] = f2bf(v.x); t[r][c + 1] = f2bf(v.y);
    t[r][c + 2] = f2bf(v.z); t[r][c + 3] = f2bf(v.w);
  }
  __syncthreads();
  u16* dst = wbt + ((size_t)e << 20);
#pragma unroll
  for (int p = 0; p < 4; ++p) {
    int orow = r_ + p * 16;
    ushort4 u;
    u.x = t[c + 0][orow]; u.y = t[c + 1][orow];
    u.z = t[c + 2][orow]; u.w = t[c + 3][orow];
    *reinterpret_cast<ushort4*>(dst + (size_t)(o0 + orow) * 1024 + i0 + c) = u;
  }
}

// ---------------- kernel 3: Horner-rescale expert GEMM --------------------
// acc accumulates raw S_e via MFMA; at each expert boundary acc *= w'_e/w'_e+1
// (per-row, from LDS table rl); epilogue y = w'_7*acc + sum_e w_e*bias_e.
// BM=BN=256 BK=64, 512 thr = 8 waves (2M x 4N), wave -> 128x64, acc 128 VGPR.
// Tile t (t=e*16+k): 4 phases x {ds_reads(8/4); [P0: 8 GLDS burst for t+1];
// barrier; lgkm(0); sched_barrier; setprio(1); 16 MFMA; setprio(0);
// [P3: vmcnt(0)]; barrier}.  One full drain per tile, 3 phases of cover.
// LDS (u16 elems): A dbuf @0,@16384 (16384 ea); B dbuf @32768,@49152
// (16384 ea, ends 65536); rl f32[8][256] @65536 (4096 elems).
// Total 69632 elems = 136KB.  (r8 bug: sm[61440] made B parity-1 overlap rl
// and overflow the block -> garbage ratios; fixed here.)
__global__ __launch_bounds__(512, 2)
void zgemm(const u16* __restrict__ xb, const u16* __restrict__ wbt,
           const float* __restrict__ wts, const float* __restrict__ bias,
           float* __restrict__ y) {
  __shared__ u16 sm[69632];
  char* smb = (char*)sm;
  float* rl = (float*)(sm + 65536);          // byte 131072

  const int tid = threadIdx.x;
  const int l   = tid & 63;
  const int w   = tid >> 6;
  const int wm  = w >> 2;                    // 0..1
  const int wn  = w & 3;                     // 0..3
  const int x8  = blockIdx.x & 7;            // XCD residue
  const int jj  = blockIdx.x >> 3;           // 0..31
  const int n0  = (x8 >> 1) * 256;           // XCD-pair owns one B-panel (4MB)
  const int b0  = (((x8 & 1) << 5) + jj) << 8;

  // ---- ratio table rl[e][256]: e<7 -> w'_e/w'_{e+1}; rl[7] = w'_7
#pragma unroll
  for (int i = 0; i < 4; ++i) {
    const int flat = tid + i * 512;
    const int e = flat & 7, r = flat >> 3;
    const float* wr = wts + (size_t)(b0 + r) * EXPERTS;
    float we = fmaxf(wr[e], 1e-20f);
    float rr = (e < 7) ? we / fmaxf(wr[e + 1], 1e-20f) : we;
    rl[e * 256 + r] = rr;
  }

  // ---- staging geometry (pre-swizzled global source, linear GLDS dest)
  const int rb    = (w << 3) + (l >> 3);              // 0..63
  const int chunk = ((l & 7) ^ (l >> 3)) << 3;
  const u16* pAg = xb  + (size_t)(b0 + rb) * IN_DIM + chunk;
  const u16* pBg = wbt + (size_t)(n0 + rb) * 1024 + chunk;

  // ---- fragment read keys
  const int l15  = l & 15;
  const int kb0  = (((l >> 4) << 4)) ^ ((l & 7) << 4);   // kf0; kf1 = ^64
  const int arow = (wm * 128 + l15) * 128;               // + m*2048
  const int brow = (wn * 64 + l15) * 128;                // + n*2048
  const int wlo  = (wm << 9) + ((l >> 4) << 4);          // rl byte off + m*64

  f32x4 acc[8][4];
#pragma unroll
  for (int m = 0; m < 8; ++m)
#pragma unroll
    for (int n = 0; n < 4; ++n) acc[m][n] = (f32x4){0.f, 0.f, 0.f, 0.f};

#define STG_A(q, dstE, ev_kv)                                              \
  GLDS16(pAg + (size_t)((q) * 64) * 1024 + (ev_kv),                        \
         sm + (dstE) + (q) * 4096 + (w << 9))
#define STG_B(q, dstE, off)                                                \
  GLDS16(pBg + (off) + (size_t)((q) * 64) * 1024,                          \
         sm + (dstE) + (q) * 4096 + (w << 9))

  // ---- prologue: tile 0 (e=0,k=0) -> parity-0 buffers; full drain
  STG_A(0, 0, 0); STG_A(1, 0, 0); STG_A(2, 0, 0); STG_A(3, 0, 0);
  STG_B(0, 32768, 0); STG_B(1, 32768, 0); STG_B(2, 32768, 0); STG_B(3, 32768, 0);
  asm volatile("s_waitcnt vmcnt(0)" ::: "memory");
  asm volatile("s_waitcnt lgkmcnt(0)" ::: "memory");   // rl ds_writes drained
  __builtin_amdgcn_s_barrier();

#define CLUSTER(AV, BV, MB)                                                \
  __builtin_amdgcn_s_barrier();                                            \
  asm volatile("s_waitcnt lgkmcnt(0)" ::: "memory");                       \
  __builtin_amdgcn_sched_barrier(0);                                       \
  __builtin_amdgcn_s_setprio(1);                                           \
  _Pragma("unroll")                                                        \
  for (int m = 0; m < 4; ++m)                                              \
    _Pragma("unroll")                                                      \
    for (int n = 0; n < 4; ++n)                                            \
      acc[(MB) + m][n] = MFMA_BF16(AV[m], BV[n], acc[(MB) + m][n], 0, 0, 0); \
  __builtin_amdgcn_s_setprio(0);

#pragma unroll 1
  for (int t = 0; t < 128; ++t) {
    const int tn  = (t + 1) & 127;                 // wrap at 127 (harmless)
    const int e1  = tn >> 4, k1 = tn & 15;
    const int ArB = (t & 1) << 15;                 // A read base (bytes)
    const int AwE = ((t + 1) & 1) << 14;           // A write base (elems)
    const int BrB = 65536 + ((t & 1) << 15);       // B read base (bytes)
    const int BwE = 32768 + (((t + 1) & 1) << 14); // B write base (elems)
    const size_t aoffg = (size_t)k1 * 64;
    const size_t boffg = (size_t)e1 * 1048576 + (size_t)k1 * 64;

    bf16x8 a[4], b[4];

    // ---------------- P0 : kf0, m0-3 (burst-stage tile t+1) ----------------
#pragma unroll
    for (int m = 0; m < 4; ++m)
      a[m] = *(const bf16x8*)(smb + ArB + arow + m * 2048 + kb0);
#pragma unroll
    for (int n = 0; n < 4; ++n)
      b[n] = *(const bf16x8*)(smb + BrB + brow + n * 2048 + kb0);
    STG_A(0, AwE, aoffg); STG_A(1, AwE, aoffg);
    STG_A(2, AwE, aoffg); STG_A(3, AwE, aoffg);
    STG_B(0, BwE, boffg); STG_B(1, BwE, boffg);
    STG_B(2, BwE, boffg); STG_B(3, BwE, boffg);
    CLUSTER(a, b, 0)
    __builtin_amdgcn_s_barrier();

    // ---------------- P1 : kf0, m4-7 ----------------
    bf16x8 a2[4];
#pragma unroll
    for (int m = 0; m < 4; ++m)
      a2[m] = *(const bf16x8*)(smb + ArB + arow + (m + 4) * 2048 + kb0);
    CLUSTER(a2, b, 4)
    __builtin_amdgcn_s_barrier();

    // ---------------- P2 : kf1, m0-3 ----------------
    bf16x8 b2[4];
#pragma unroll
    for (int m = 0; m < 4; ++m)
      a[m] = *(const bf16x8*)(smb + ArB + arow + m * 2048 + (kb0 ^ 64));
#pragma unroll
    for (int n = 0; n < 4; ++n)
      b2[n] = *(const bf16x8*)(smb + BrB + brow + n * 2048 + (kb0 ^ 64));
    CLUSTER(a, b2, 0)
    __builtin_amdgcn_s_barrier();

    // ---------------- P3 : kf1, m4-7 (full drain before closing barrier) ---
#pragma unroll
    for (int m = 0; m < 4; ++m)
      a2[m] = *(const bf16x8*)(smb + ArB + arow + (m + 4) * 2048 + (kb0 ^ 64));
    CLUSTER(a2, b2, 4)
    asm volatile("s_waitcnt vmcnt(0)" ::: "memory");   // t+1 staging published
    __builtin_amdgcn_s_barrier();

    // ---- expert boundary: acc *= w'_e / w'_{e+1}  (7 times total)
    if ((t & 15) == 15 && t != 127) {
      const int e = t >> 4;
#pragma unroll
      for (int m = 0; m < 8; ++m) {
        const f32x4 rv = *(const f32x4*)(smb + 131072 + e * 1024 + wlo + m * 64);
#pragma unroll
        for (int n = 0; n < 4; ++n) acc[m][n] *= rv;
      }
    }
  }
  asm volatile("s_waitcnt vmcnt(0)" ::: "memory");

  // ---- epilogue: y = w'_7 * acc + sum_e w_e * bias_e
  float bv[4][8];
#pragma unroll
  for (int n = 0; n < 4; ++n) {
    const int c = n0 + wn * 64 + n * 16 + l15;
#pragma unroll
    for (int ee = 0; ee < 8; ++ee) bv[n][ee] = bias[ee * OUT_DIM + c];
  }
#pragma unroll
  for (int m = 0; m < 8; ++m) {
    const f32x4 rv7 = *(const f32x4*)(smb + 131072 + 7 * 1024 + wlo + m * 64);
    const int r0 = b0 + wm * 128 + m * 16 + ((l >> 4) << 2);
#pragma unroll
    for (int j = 0; j < 4; ++j) {
      const float* wr = wts + (size_t)(r0 + j) * EXPERTS;
      float w8[8];
#pragma unroll
      for (int ee = 0; ee < 8; ++ee) w8[ee] = wr[ee];
#pragma unroll
      for (int n = 0; n < 4; ++n) {
        const int c = n0 + wn * 64 + n * 16 + l15;
        float v = acc[m][n][j] * rv7[j];
#pragma unroll
        for (int ee = 0; ee < 8; ++ee) v += w8[ee] * bv[n][ee];
        y[(size_t)(r0 + j) * OUT_DIM + c] = v;
      }
    }
  }
}

extern "C" void kernel_launch(void* const* d_in, const int* in_sizes, int n_in,
                              void* d_out, int out_size, void* d_ws, size_t ws_size,
                              hipStream_t stream) {
  const float* x    = (const float*)d_in[0];
  const float* wts  = (const float*)d_in[1];
  const float* W    = (const float*)d_in[2];
  const float* bias = (const float*)d_in[3];
  float* y = (float*)d_out;

  const size_t xb_elems = (size_t)BATCH * IN_DIM;                 // 32 MB bf16
  const size_t wb_elems = (size_t)EXPERTS * IN_DIM * OUT_DIM;     // 16 MB bf16
  if (ws_size < (xb_elems + wb_elems) * sizeof(u16)) return;      // loud failure
  u16* xb  = (u16*)d_ws;
  u16* wbt = xb + xb_elems;

  cvt_x<<<(BATCH * IN_DIM) / (4 * 256), 256, 0, stream>>>(x, xb);
  cvt_w<<<dim3(IN_DIM / 64, OUT_DIM / 64, EXPERTS), 256, 0, stream>>>(W, wbt);
  zgemm<<<dim3(256), 512, 0, stream>>>(xb, wbt, wts, bias, y);
}

// Round 10
// 259.686 us; speedup vs baseline: 1.3814x; 1.1085x over previous
//
#include <hip/hip_runtime.h>
#include <hip/hip_bf16.h>
#include <stdint.h>

#define BATCH   16384
#define EXPERTS 8
#define IN_DIM  1024
#define OUT_DIM 1024

typedef unsigned short u16;
typedef short  bf16x8 __attribute__((ext_vector_type(8)));
typedef float  f32x4  __attribute__((ext_vector_type(4)));

__device__ __forceinline__ u16 f2bf(float f) {
  uint32_t u = __float_as_uint(f);
  u += 0x7fffu + ((u >> 16) & 1u);   // RNE
  return (u16)(u >> 16);
}

#define GLDS16(g, l)                                                      \
  __builtin_amdgcn_global_load_lds(                                       \
      (const __attribute__((address_space(1))) void*)(g),                 \
      (__attribute__((address_space(3))) void*)(l), 16, 0, 0)

#define MFMA_BF16 __builtin_amdgcn_mfma_f32_16x16x32_bf16
#define SB0 __builtin_amdgcn_sched_barrier(0)
#define LGKM(N) asm volatile("s_waitcnt lgkmcnt(" #N ")" ::: "memory")

// ---------------- kernel 1: x fp32 -> bf16 ----------------
__global__ void cvt_x(const float* __restrict__ x, u16* __restrict__ xb) {
  size_t i = ((size_t)blockIdx.x * 256 + threadIdx.x) * 4;
  float4 v = *reinterpret_cast<const float4*>(x + i);
  ushort4 o;
  o.x = f2bf(v.x); o.y = f2bf(v.y); o.z = f2bf(v.z); o.w = f2bf(v.w);
  *reinterpret_cast<ushort4*>(xb + i) = o;
}

// ------- kernel 2: W[e][i][o] fp32 -> Wbt[e][o][i] bf16 (transpose) -------
__global__ void cvt_w(const float* __restrict__ W, u16* __restrict__ wbt) {
  __shared__ u16 t[64][72];
  const int e  = blockIdx.z;
  const int i0 = blockIdx.x * 64;
  const int o0 = blockIdx.y * 64;
  const int tid = threadIdx.x;
  const int c  = (tid & 15) * 4;
  const int r_ = tid >> 4;
  const float* src = W + ((size_t)e << 20);
#pragma unroll
  for (int p = 0; p < 4; ++p) {
    int r = r_ + p * 16;
    float4 v = *reinterpret_cast<const float4*>(src + (size_t)(i0 + r) * 1024 + o0 + c);
    t[r][c + 0] = f2bf(v.x); t[r][c + 1] = f2bf(v.y);
    t[r][c + 2] = f2bf(v.z); t[r][c + 3] = f2bf(v.w);
  }
  __syncthreads();
  u16* dst = wbt + ((size_t)e << 20);
#pragma unroll
  for (int p = 0; p < 4; ++p) {
    int orow = r_ + p * 16;
    ushort4 u;
    u.x = t[c + 0][orow]; u.y = t[c + 1][orow];
    u.z = t[c + 2][orow]; u.w = t[c + 3][orow];
    *reinterpret_cast<ushort4*>(dst + (size_t)(o0 + orow) * 1024 + i0 + c) = u;
  }
}

// ---------------- kernel 3: Horner-rescale expert GEMM, 1-barrier tile ----
// BM=BN=256 BK=64, 512 thr = 8 waves (2M x 4N), wave -> 128x64, acc 128.
// Whole-tile double buffers -> intra-tile barriers unnecessary. Per tile:
//   top: issue F0(8) F1(4) ds_reads + 8 GLDS (t+1, opposite parity)
//   lgkm(4)  -> MFMA P0 (F2 issued under it)
//   lgkm(8)  -> MFMA P1 (F3 issued under it)
//   lgkm(4)  -> MFMA P2
//   lgkm(0)  -> MFMA P3
//   vmcnt(0); ONE barrier (publish staging)
// Counted lgkm relies on in-order DS completion; GLDS counts vmcnt only;
// rescale's rl reads force-drained so counts stay exact.
// LDS (u16 elems): A dbuf @0,@16384; B dbuf @32768,@49152; rl @65536 (4096).
// Total 69632 elems = 136KB.
__global__ __launch_bounds__(512, 2)
void zgemm(const u16* __restrict__ xb, const u16* __restrict__ wbt,
           const float* __restrict__ wts, const float* __restrict__ bias,
           float* __restrict__ y) {
  __shared__ u16 sm[69632];
  char* smb = (char*)sm;
  float* rl = (float*)(sm + 65536);          // byte 131072

  const int tid = threadIdx.x;
  const int l   = tid & 63;
  const int w   = tid >> 6;
  const int wm  = w >> 2;                    // 0..1
  const int wn  = w & 3;                     // 0..3
  const int x8  = blockIdx.x & 7;            // XCD residue
  const int jj  = blockIdx.x >> 3;           // 0..31
  const int n0  = (x8 >> 1) * 256;           // XCD-pair owns one B-panel
  const int b0  = (((x8 & 1) << 5) + jj) << 8;

  // ---- ratio table rl[e][256]: e<7 -> w'_e/w'_{e+1}; rl[7] = w'_7
#pragma unroll
  for (int i = 0; i < 4; ++i) {
    const int flat = tid + i * 512;
    const int e = flat & 7, r = flat >> 3;
    const float* wr = wts + (size_t)(b0 + r) * EXPERTS;
    float we = fmaxf(wr[e], 1e-20f);
    float rr = (e < 7) ? we / fmaxf(wr[e + 1], 1e-20f) : we;
    rl[e * 256 + r] = rr;
  }

  // ---- staging geometry (pre-swizzled global source, linear GLDS dest)
  const int rb    = (w << 3) + (l >> 3);              // 0..63
  const int chunk = ((l & 7) ^ (l >> 3)) << 3;
  const u16* pAg = xb  + (size_t)(b0 + rb) * IN_DIM + chunk;
  const u16* pBg = wbt + (size_t)(n0 + rb) * 1024 + chunk;

  // ---- fragment read keys
  const int l15  = l & 15;
  const int kb0  = (((l >> 4) << 4)) ^ ((l & 7) << 4);   // kf0; kf1 = ^64
  const int arow = (wm * 128 + l15) * 128;               // + m*2048
  const int brow = (wn * 64 + l15) * 128;                // + n*2048
  const int wlo  = (wm << 9) + ((l >> 4) << 4);          // rl byte off + m*64

  f32x4 acc[8][4];
#pragma unroll
  for (int m = 0; m < 8; ++m)
#pragma unroll
    for (int n = 0; n < 4; ++n) acc[m][n] = (f32x4){0.f, 0.f, 0.f, 0.f};

#define STG_A(q, dstE, ev_kv)                                              \
  GLDS16(pAg + (size_t)((q) * 64) * 1024 + (ev_kv),                        \
         sm + (dstE) + (q) * 4096 + (w << 9))
#define STG_B(q, dstE, off)                                                \
  GLDS16(pBg + (off) + (size_t)((q) * 64) * 1024,                          \
         sm + (dstE) + (q) * 4096 + (w << 9))

  // ---- prologue: tile 0 -> parity-0 buffers; full drain; publish
  STG_A(0, 0, 0); STG_A(1, 0, 0); STG_A(2, 0, 0); STG_A(3, 0, 0);
  STG_B(0, 32768, 0); STG_B(1, 32768, 0); STG_B(2, 32768, 0); STG_B(3, 32768, 0);
  asm volatile("s_waitcnt vmcnt(0)" ::: "memory");
  LGKM(0);                                   // rl ds_writes drained
  __builtin_amdgcn_s_barrier();

#define MM(AV, BV, MB)                                                     \
  __builtin_amdgcn_s_setprio(1);                                           \
  _Pragma("unroll")                                                        \
  for (int m = 0; m < 4; ++m)                                              \
    _Pragma("unroll")                                                      \
    for (int n = 0; n < 4; ++n)                                            \
      acc[(MB) + m][n] = MFMA_BF16(AV[m], BV[n], acc[(MB) + m][n], 0, 0, 0); \
  __builtin_amdgcn_s_setprio(0);

#pragma unroll 1
  for (int t = 0; t < 128; ++t) {
    const int tn  = (t + 1) & 127;                 // wrap at 127 (harmless)
    const int e1  = tn >> 4, k1 = tn & 15;
    const int ArB = (t & 1) << 15;                 // A read base (bytes)
    const int AwE = ((t + 1) & 1) << 14;           // A write base (elems)
    const int BrB = 65536 + ((t & 1) << 15);       // B read base (bytes)
    const int BwE = 32768 + (((t + 1) & 1) << 14); // B write base (elems)
    const size_t aoffg = (size_t)k1 * 64;
    const size_t boffg = (size_t)e1 * 1048576 + (size_t)k1 * 64;

    bf16x8 a0[4], b0v[4], a1[4], a2v[4], b1v[4], a3[4];

    // ---- tile top: F0 (a m0-3 kf0, b kf0) + F1 (a m4-7 kf0) + 8 GLDS
#pragma unroll
    for (int m = 0; m < 4; ++m)
      a0[m] = *(const bf16x8*)(smb + ArB + arow + m * 2048 + kb0);
#pragma unroll
    for (int n = 0; n < 4; ++n)
      b0v[n] = *(const bf16x8*)(smb + BrB + brow + n * 2048 + kb0);
#pragma unroll
    for (int m = 0; m < 4; ++m)
      a1[m] = *(const bf16x8*)(smb + ArB + arow + (m + 4) * 2048 + kb0);
    STG_A(0, AwE, aoffg); STG_A(1, AwE, aoffg);
    STG_A(2, AwE, aoffg); STG_A(3, AwE, aoffg);
    STG_B(0, BwE, boffg); STG_B(1, BwE, boffg);
    STG_B(2, BwE, boffg); STG_B(3, BwE, boffg);

    LGKM(4); SB0;                         // F0 done (F1 in flight)
    // F2 issue (a m0-3 kf1, b kf1) overlaps MFMA P0
#pragma unroll
    for (int m = 0; m < 4; ++m)
      a2v[m] = *(const bf16x8*)(smb + ArB + arow + m * 2048 + (kb0 ^ 64));
#pragma unroll
    for (int n = 0; n < 4; ++n)
      b1v[n] = *(const bf16x8*)(smb + BrB + brow + n * 2048 + (kb0 ^ 64));
    MM(a0, b0v, 0)

    LGKM(8); SB0;                         // F1 done (F2 in flight)
    // F3 issue (a m4-7 kf1) overlaps MFMA P1
#pragma unroll
    for (int m = 0; m < 4; ++m)
      a3[m] = *(const bf16x8*)(smb + ArB + arow + (m + 4) * 2048 + (kb0 ^ 64));
    MM(a1, b0v, 4)

    LGKM(4); SB0;                         // F2 done (F3 in flight)
    MM(a2v, b1v, 0)

    LGKM(0); SB0;                         // F3 done
    MM(a3, b1v, 4)

    asm volatile("s_waitcnt vmcnt(0)" ::: "memory");   // t+1 staging landed
    __builtin_amdgcn_s_barrier();                      // publish (only barrier)

    // ---- expert boundary: acc *= w'_e / w'_{e+1}  (7 times total)
    if ((t & 15) == 15 && t != 127) {
      const int e = t >> 4;
#pragma unroll
      for (int m = 0; m < 8; ++m) {
        const f32x4 rv = *(const f32x4*)(smb + 131072 + e * 1024 + wlo + m * 64);
#pragma unroll
        for (int n = 0; n < 4; ++n) acc[m][n] *= rv;
      }
      LGKM(0); SB0;                       // keep next tile's lgkm ledger exact
    }
  }
  asm volatile("s_waitcnt vmcnt(0)" ::: "memory");

  // ---- epilogue: y = w'_7 * acc + sum_e w_e * bias_e
  float bv[4][8];
#pragma unroll
  for (int n = 0; n < 4; ++n) {
    const int c = n0 + wn * 64 + n * 16 + l15;
#pragma unroll
    for (int ee = 0; ee < 8; ++ee) bv[n][ee] = bias[ee * OUT_DIM + c];
  }
#pragma unroll
  for (int m = 0; m < 8; ++m) {
    const f32x4 rv7 = *(const f32x4*)(smb + 131072 + 7 * 1024 + wlo + m * 64);
    const int r0 = b0 + wm * 128 + m * 16 + ((l >> 4) << 2);
#pragma unroll
    for (int j = 0; j < 4; ++j) {
      const float* wr = wts + (size_t)(r0 + j) * EXPERTS;
      float w8[8];
#pragma unroll
      for (int ee = 0; ee < 8; ++ee) w8[ee] = wr[ee];
#pragma unroll
      for (int n = 0; n < 4; ++n) {
        const int c = n0 + wn * 64 + n * 16 + l15;
        float v = acc[m][n][j] * rv7[j];
#pragma unroll
        for (int ee = 0; ee < 8; ++ee) v += w8[ee] * bv[n][ee];
        y[(size_t)(r0 + j) * OUT_DIM + c] = v;
      }
    }
  }
}

extern "C" void kernel_launch(void* const* d_in, const int* in_sizes, int n_in,
                              void* d_out, int out_size, void* d_ws, size_t ws_size,
                              hipStream_t stream) {
  const float* x    = (const float*)d_in[0];
  const float* wts  = (const float*)d_in[1];
  const float* W    = (const float*)d_in[2];
  const float* bias = (const float*)d_in[3];
  float* y = (float*)d_out;

  const size_t xb_elems = (size_t)BATCH * IN_DIM;                 // 32 MB bf16
  const size_t wb_elems = (size_t)EXPERTS * IN_DIM * OUT_DIM;     // 16 MB bf16
  if (ws_size < (xb_elems + wb_elems) * sizeof(u16)) return;      // loud failure
  u16* xb  = (u16*)d_ws;
  u16* wbt = xb + xb_elems;

  cvt_x<<<(BATCH * IN_DIM) / (4 * 256), 256, 0, stream>>>(x, xb);
  cvt_w<<<dim3(IN_DIM / 64, OUT_DIM / 64, EXPERTS), 256, 0, stream>>>(W, wbt);
  zgemm<<<dim3(256), 512, 0, stream>>>(xb, wbt, wts, bias, y);
}